// Round 4
// baseline (100325.128 us; speedup 1.0000x reference)
//
#include <hip/hip_runtime.h>
#include <math.h>

// Seq2seq LSTM: 5-layer stack, HID=80, 336 enc + 48 dec steps.
// R4: split each gate row across 2 threads (k-halves) so register-resident
//     weight prefetch needs only ~80 VGPRs of weights -> no spill (R3 spilled
//     230-reg live set to scratch: 29.5 GB HBM traffic). Pair partials are
//     combined via __shfl_xor(.,1); activations branchless and split per half.
#define LAYERS 5
#define HID    80
#define GATES  320      // 4*HID, order [i|f|g|o]
#define INDIM  4
#define BATCH  512
#define SEQLEN 336
#define PREDLEN 48
#define NB     4        // batch elems per block
#define NTHR   640      // 2 threads per gate row
#define HCHUNK 10       // float4 chunks per half-row
#define KHALF  40       // floats per half-row

static_assert(NTHR == 2 * GATES, "two threads per gate row");
static_assert(2 * KHALF == HID, "half split");
static_assert(HCHUNK * 4 == KHALF, "chunking");

// branchless gate activation: sigmoid(v) or tanh(v) = 1 - 2*sigmoid(-2v)
__device__ __forceinline__ float gate_act(float v, bool tg) {
    const float e = __expf(tg ? 2.0f * v : -v);
    const float r = 1.0f / (1.0f + e);
    return tg ? 1.0f - 2.0f * r : r;
}
__device__ __forceinline__ float tanh_fast(float v) {
    return 1.0f - 2.0f / (1.0f + __expf(2.0f * v));
}

// 16 FMAs: one float4 weight chunk vs 4 batches' h[K..K+3] (LDS broadcast reads)
#define DOT4(W, HBASE, K)                                                        \
    do {                                                                         \
        const float* _hb = (HBASE);                                              \
        const float4 h0 = *(const float4*)&_hb[0 * HID + (K)];                   \
        const float4 h1 = *(const float4*)&_hb[1 * HID + (K)];                   \
        const float4 h2 = *(const float4*)&_hb[2 * HID + (K)];                   \
        const float4 h3 = *(const float4*)&_hb[3 * HID + (K)];                   \
        a0 += (W).x * h0.x + (W).y * h0.y + (W).z * h0.z + (W).w * h0.w;         \
        a1 += (W).x * h1.x + (W).y * h1.y + (W).z * h1.z + (W).w * h1.w;         \
        a2 += (W).x * h2.x + (W).y * h2.y + (W).z * h2.z + (W).w * h2.w;         \
        a3 += (W).x * h3.x + (W).y * h3.y + (W).z * h3.z + (W).w * h3.w;         \
    } while (0)

__global__ __launch_bounds__(NTHR, 3) void lstm_s2s(
    const float* __restrict__ x,    const float* __restrict__ ff,
    const float* __restrict__ eW0,  const float* __restrict__ eWih,
    const float* __restrict__ eWhh, const float* __restrict__ ebih,
    const float* __restrict__ ebhh,
    const float* __restrict__ dW0,  const float* __restrict__ dWih,
    const float* __restrict__ dWhh, const float* __restrict__ dbih,
    const float* __restrict__ dbhh,
    const float* __restrict__ fcW,  const float* __restrict__ fcb,
    float* __restrict__ out)
{
    __shared__ __align__(16) float sh[LAYERS][NB][HID];   // hidden state
    __shared__ __align__(16) float sc[LAYERS][NB][HID];   // cell state
    __shared__ __align__(16) float sg[NB][GATES];         // activated gates
    __shared__ __align__(16) float sx[NB][INDIM];         // step input / dec feedback

    const int tid  = threadIdx.x;
    const int g    = tid >> 1;       // gate row
    const int half = tid & 1;        // k-half of the row
    const int koff = half * KHALF;
    const int b0   = blockIdx.x * NB;

    for (int i = tid; i < LAYERS * NB * HID; i += NTHR) {
        (&sh[0][0][0])[i] = 0.0f;
        (&sc[0][0][0])[i] = 0.0f;
    }

    const bool is_tanh_gate = (g >= 2 * HID) && (g < 3 * HID);
    const int  unb          = tid / HID;   // update mapping (valid for tid<NB*HID)
    const int  uj           = tid % HID;

    // bias sums [enc/dec][layer] — applied by half==0 only
    float bsum[2][LAYERS];
    #pragma unroll
    for (int l = 0; l < LAYERS; ++l) {
        bsum[0][l] = ebih[l * GATES + g] + ebhh[l * GATES + g];
        bsum[1][l] = dbih[l * GATES + g] + dbhh[l * GATES + g];
    }

    // register-resident half-rows for the CURRENT stage
    float4 whhR[HCHUNK];
    float4 wihR[HCHUNK];
    float4 w0R;

    #pragma unroll
    for (int i = 0; i < HCHUNK; ++i)
        wihR[i] = make_float4(0.f, 0.f, 0.f, 0.f);   // written at (t,0) before use

    // initial prefetch for stage (t=0, l=0)
    w0R = *(const float4*)&eW0[g * INDIM];
    #pragma unroll
    for (int i = 0; i < HCHUNK; ++i)
        whhR[i] = *(const float4*)&eWhh[(size_t)g * HID + koff + 4 * i];

    for (int t = 0; t < SEQLEN + PREDLEN; ++t) {
        const bool enc = (t < SEQLEN);

        if (enc && tid < NB * INDIM) {
            const int nb = tid / INDIM, k = tid % INDIM;
            sx[nb][k] = x[((size_t)(b0 + nb) * SEQLEN + t) * INDIM + k];
        }
        __syncthreads();   // sx staged / dec feedback + updated state visible

        for (int l = 0; l < LAYERS; ++l) {
            // ---- next-stage coordinates (for prefetch) ----
            int nl = l + 1, nt = t;
            if (nl == LAYERS) { nl = 0; ++nt; }
            const bool nenc    = (nt < SEQLEN);
            const bool valid_n = (nt < SEQLEN + PREDLEN);
            const float* nWhh  = (valid_n ? ((nenc ? eWhh : dWhh) + ((size_t)nl * GATES + g) * HID)
                                          : (eWhh + (size_t)g * HID))   // clamp: loaded, unused
                                 + koff;

            const float bias = half ? 0.0f : (enc ? bsum[0][l] : bsum[1][l]);
            float a0 = bias, a1 = bias, a2 = bias, a3 = bias;

            // ---- Whh half-dot (reads old sh[l]) with interleaved whh refill ----
            #pragma unroll
            for (int i = 0; i < HCHUNK; ++i) {
                const float4 w = whhR[i];
                DOT4(w, &sh[l][0][0], koff + 4 * i);
                whhR[i] = *(const float4*)&nWhh[4 * i];
            }

            // ---- input half-dot ----
            if (l == 0) {
                if (half == 0) {
                    const float4 w = w0R;
                    a0 += w.x * sx[0][0] + w.y * sx[0][1] + w.z * sx[0][2] + w.w * sx[0][3];
                    a1 += w.x * sx[1][0] + w.y * sx[1][1] + w.z * sx[1][2] + w.w * sx[1][3];
                    a2 += w.x * sx[2][0] + w.y * sx[2][1] + w.z * sx[2][2] + w.w * sx[2][3];
                    a3 += w.x * sx[3][0] + w.y * sx[3][1] + w.z * sx[3][2] + w.w * sx[3][3];
                }
                // refill wihR for next stage (nl==1 always: Wih[0] row g)
                const float* nWih = (nenc ? eWih : dWih) + (size_t)g * HID + koff;
                #pragma unroll
                for (int i = 0; i < HCHUNK; ++i)
                    wihR[i] = *(const float4*)&nWih[4 * i];
            } else {
                #pragma unroll
                for (int i = 0; i < HCHUNK; ++i) {
                    const float4 w = wihR[i];
                    DOT4(w, &sh[l - 1][0][0], koff + 4 * i);
                }
                if (nl > 0) {       // refill wihR for next stage
                    const float* nWih = (nenc ? eWih : dWih)
                                      + ((size_t)(nl - 1) * GATES + g) * HID + koff;
                    #pragma unroll
                    for (int i = 0; i < HCHUNK; ++i)
                        wihR[i] = *(const float4*)&nWih[4 * i];
                } else if (valid_n) {  // next is (t+1, 0): refill W0 row
                    w0R = *(const float4*)&((nenc ? eW0 : dW0)[g * INDIM]);
                }
            }

            // ---- pair combine (lanes tid, tid^1) ----
            a0 += __shfl_xor(a0, 1);
            a1 += __shfl_xor(a1, 1);
            a2 += __shfl_xor(a2, 1);
            a3 += __shfl_xor(a3, 1);

            // ---- activation: half h handles batches 2h, 2h+1 ----
            const float u0 = half ? a2 : a0;
            const float u1 = half ? a3 : a1;
            const float v0 = gate_act(u0, is_tanh_gate);
            const float v1 = gate_act(u1, is_tanh_gate);
            sg[2 * half + 0][g] = v0;
            sg[2 * half + 1][g] = v1;
            __syncthreads();   // gates ready

            // ---- state update (threads 0..319) ----
            if (tid < NB * HID) {
                const float iv = sg[unb][uj];
                const float fv = sg[unb][uj + HID];
                const float gv = sg[unb][uj + 2 * HID];
                const float ov = sg[unb][uj + 3 * HID];
                const float cn = fv * sc[l][unb][uj] + iv * gv;
                const float hn = ov * tanh_fast(cn);
                sc[l][unb][uj] = cn;
                sh[l][unb][uj] = hn;
            }
            __syncthreads();   // h/c updated before next stage reads them
        }

        if (!enc) {
            const int td = t - SEQLEN;
            if (tid < NB) {
                float s = fcb[0];
                #pragma unroll
                for (int j = 0; j < HID; j += 4) {
                    const float4 wv = *(const float4*)&fcW[j];
                    const float4 hv = *(const float4*)&sh[LAYERS - 1][tid][j];
                    s += wv.x * hv.x + wv.y * hv.y + wv.z * hv.z + wv.w * hv.w;
                }
                out[(size_t)(b0 + tid) * PREDLEN + td] = s;
                sx[tid][0] = s;                       // feedback feature 0
            } else if (tid >= 64 && tid < 64 + NB * 3) {
                const int q = tid - 64;
                const int nb = q / 3, k = q % 3;
                sx[nb][k + 1] = ff[((size_t)(b0 + nb) * PREDLEN + td) * 3 + k];
            }
            // top-of-loop __syncthreads() covers these sx writes
        }
    }
}

extern "C" void kernel_launch(void* const* d_in, const int* in_sizes, int n_in,
                              void* d_out, int out_size, void* d_ws, size_t ws_size,
                              hipStream_t stream) {
    const float* x    = (const float*)d_in[0];
    const float* ff   = (const float*)d_in[1];
    const float* eW0  = (const float*)d_in[2];
    const float* eWih = (const float*)d_in[3];
    const float* eWhh = (const float*)d_in[4];
    const float* ebih = (const float*)d_in[5];
    const float* ebhh = (const float*)d_in[6];
    const float* dW0  = (const float*)d_in[7];
    const float* dWih = (const float*)d_in[8];
    const float* dWhh = (const float*)d_in[9];
    const float* dbih = (const float*)d_in[10];
    const float* dbhh = (const float*)d_in[11];
    const float* fcW  = (const float*)d_in[12];
    const float* fcb  = (const float*)d_in[13];

    lstm_s2s<<<BATCH / NB, NTHR, 0, stream>>>(
        x, ff, eW0, eWih, eWhh, ebih, ebhh,
        dW0, dWih, dWhh, dbih, dbhh, fcW, fcb, (float*)d_out);
}

// Round 5
// 13188.614 us; speedup vs baseline: 7.6070x; 7.6070x over previous
//
#include <hip/hip_runtime.h>
#include <math.h>

// Seq2seq LSTM: 5-layer stack, HID=80, 336 enc + 48 dec steps.
// R5: NO register-resident weights (R3/R4 both spilled catastrophically).
//     640 threads = (2 rows) x (4 k-quarters) per gate-row-pair; weights are
//     loaded transiently (load->FMA) like R1 which had VGPR=48/no spill.
//     LDS h-reads halved vs R1 (reused across the 2 rows); quartet partials
//     combined via 3-shfl reduce-scatter so lane q finishes batch q's gates.
#define LAYERS  5
#define HID     80
#define GATES   320     // 4*HID, order [i|f|g|o]
#define INDIM   4
#define BATCH   512
#define SEQLEN  336
#define PREDLEN 48
#define NB      4       // batch elems per block
#define NTHR    640     // 160 row-pairs x 4 k-quarters
#define QK      20      // k-floats per quarter

__device__ __forceinline__ float gate_act(float v, bool tg) {
    const float e = __expf(tg ? 2.0f * v : -v);
    const float r = 1.0f / (1.0f + e);
    return tg ? 1.0f - 2.0f * r : r;       // tanh(v) : sigmoid(v)
}
__device__ __forceinline__ float tanh_fast(float v) {
    return 1.0f - 2.0f / (1.0f + __expf(2.0f * v));
}

// one k-chunk (4 floats) of rows {r0, r0+1} against 4 batches' h: 32 FMA, 6 loads
#define CHUNK(WPTR, HPTR, I)                                                     \
    do {                                                                         \
        const float4 wA = *(const float4*)((WPTR) + 4 * (I));                    \
        const float4 wB = *(const float4*)((WPTR) + HID + 4 * (I));              \
        const float* _h = (HPTR);                                                \
        const float4 h0 = *(const float4*)(_h + 0 * HID + 4 * (I));              \
        const float4 h1 = *(const float4*)(_h + 1 * HID + 4 * (I));              \
        const float4 h2 = *(const float4*)(_h + 2 * HID + 4 * (I));              \
        const float4 h3 = *(const float4*)(_h + 3 * HID + 4 * (I));              \
        a00 += wA.x * h0.x + wA.y * h0.y + wA.z * h0.z + wA.w * h0.w;            \
        a01 += wA.x * h1.x + wA.y * h1.y + wA.z * h1.z + wA.w * h1.w;            \
        a02 += wA.x * h2.x + wA.y * h2.y + wA.z * h2.z + wA.w * h2.w;            \
        a03 += wA.x * h3.x + wA.y * h3.y + wA.z * h3.z + wA.w * h3.w;            \
        a10 += wB.x * h0.x + wB.y * h0.y + wB.z * h0.z + wB.w * h0.w;            \
        a11 += wB.x * h1.x + wB.y * h1.y + wB.z * h1.z + wB.w * h1.w;            \
        a12 += wB.x * h2.x + wB.y * h2.y + wB.z * h2.z + wB.w * h2.w;            \
        a13 += wB.x * h3.x + wB.y * h3.y + wB.z * h3.z + wB.w * h3.w;            \
    } while (0)

// reduce-scatter 4 values across a lane-quartet: lane q returns sum_lanes val[q]
__device__ __forceinline__ float rs4(float v0, float v1, float v2, float v3, int q) {
    float u  = (q & 1) ? v1 : v0;
    float s  = (q & 1) ? v0 : v1;
    u += __shfl_xor(s, 1);
    float u2 = (q & 1) ? v3 : v2;
    float s2 = (q & 1) ? v2 : v3;
    u2 += __shfl_xor(s2, 1);
    float k  = (q & 2) ? u2 : u;
    float s3 = (q & 2) ? u : u2;
    k += __shfl_xor(s3, 2);
    return k;
}

__global__ __launch_bounds__(NTHR) void lstm_s2s(
    const float* __restrict__ x,    const float* __restrict__ ff,
    const float* __restrict__ eW0,  const float* __restrict__ eWih,
    const float* __restrict__ eWhh, const float* __restrict__ ebih,
    const float* __restrict__ ebhh,
    const float* __restrict__ dW0,  const float* __restrict__ dWih,
    const float* __restrict__ dWhh, const float* __restrict__ dbih,
    const float* __restrict__ dbhh,
    const float* __restrict__ fcW,  const float* __restrict__ fcb,
    float* __restrict__ out)
{
    __shared__ __align__(16) float sh[LAYERS][NB][HID];   // hidden state
    __shared__ __align__(16) float sc[LAYERS][NB][HID];   // cell state
    __shared__ __align__(16) float sg[NB][GATES + 1];     // gates (+1 pad: bank spread)
    __shared__ __align__(16) float sx[NB][INDIM];         // step input / dec feedback

    const int tid = threadIdx.x;
    const int q   = tid & 3;        // k-quarter
    const int m   = tid >> 2;       // row-pair index 0..159
    const int r0  = 2 * m;          // rows r0, r0+1 (same gate class: boundaries at 80)
    const int b0  = blockIdx.x * NB;

    for (int i = tid; i < LAYERS * NB * HID; i += NTHR) {
        (&sh[0][0][0])[i] = 0.0f;
        (&sc[0][0][0])[i] = 0.0f;
    }

    const bool is_tg = (r0 >= 2 * HID) && (r0 < 3 * HID);
    const int  unb   = tid / HID;   // update mapping (tid < NB*HID)
    const int  uj    = tid % HID;

    // persistent per-thread constants: bias sums + W0 scalars (ctx: 0=enc,1=dec)
    float bs[2][LAYERS][2];
    #pragma unroll
    for (int l = 0; l < LAYERS; ++l) {
        bs[0][l][0] = ebih[l * GATES + r0]     + ebhh[l * GATES + r0];
        bs[0][l][1] = ebih[l * GATES + r0 + 1] + ebhh[l * GATES + r0 + 1];
        bs[1][l][0] = dbih[l * GATES + r0]     + dbhh[l * GATES + r0];
        bs[1][l][1] = dbih[l * GATES + r0 + 1] + dbhh[l * GATES + r0 + 1];
    }
    const float w0e0 = eW0[r0 * INDIM + q],       w0e1 = eW0[(r0 + 1) * INDIM + q];
    const float w0d0 = dW0[r0 * INDIM + q],       w0d1 = dW0[(r0 + 1) * INDIM + q];

    for (int t = 0; t < SEQLEN + PREDLEN; ++t) {
        const bool enc = (t < SEQLEN);
        const float* Wih = enc ? eWih : dWih;
        const float* Whh = enc ? eWhh : dWhh;

        if (enc && tid < NB * INDIM) {
            const int nb = tid / INDIM, k = tid % INDIM;
            sx[nb][k] = x[((size_t)(b0 + nb) * SEQLEN + t) * INDIM + k];
        }
        __syncthreads();   // sx staged / dec feedback visible

        #pragma unroll
        for (int l = 0; l < LAYERS; ++l) {
            float a00 = 0.f, a01 = 0.f, a02 = 0.f, a03 = 0.f;
            float a10 = 0.f, a11 = 0.f, a12 = 0.f, a13 = 0.f;

            // ---- Whh part: rows {r0,r0+1}, k-quarter q, vs old sh[l] ----
            {
                const float* wp = Whh + ((size_t)l * GATES + r0) * HID + q * QK;
                const float* hp = &sh[l][0][q * QK];
                #pragma unroll
                for (int i = 0; i < QK / 4; ++i) CHUNK(wp, hp, i);
            }

            // ---- input part ----
            if (l == 0) {
                // each lane handles input feature j=q; summed by rs4
                const float wa = enc ? w0e0 : w0d0;
                const float wb = enc ? w0e1 : w0d1;
                a00 += wa * sx[0][q];  a01 += wa * sx[1][q];
                a02 += wa * sx[2][q];  a03 += wa * sx[3][q];
                a10 += wb * sx[0][q];  a11 += wb * sx[1][q];
                a12 += wb * sx[2][q];  a13 += wb * sx[3][q];
            } else {
                const float* wp = Wih + ((size_t)(l - 1) * GATES + r0) * HID + q * QK;
                const float* hp = &sh[l - 1][0][q * QK];
                #pragma unroll
                for (int i = 0; i < QK / 4; ++i) CHUNK(wp, hp, i);
            }

            // ---- reduce-scatter: lane q gets batch-q totals for its 2 rows ----
            const float s0 = rs4(a00, a01, a02, a03, q);
            const float s1 = rs4(a10, a11, a12, a13, q);

            const float bias0 = enc ? bs[0][l][0] : bs[1][l][0];
            const float bias1 = enc ? bs[0][l][1] : bs[1][l][1];
            sg[q][r0]     = gate_act(s0 + bias0, is_tg);
            sg[q][r0 + 1] = gate_act(s1 + bias1, is_tg);
            __syncthreads();   // gates ready

            // ---- state update (threads 0..319) ----
            if (tid < NB * HID) {
                const float iv = sg[unb][uj];
                const float fv = sg[unb][uj + HID];
                const float gv = sg[unb][uj + 2 * HID];
                const float ov = sg[unb][uj + 3 * HID];
                const float cn = fv * sc[l][unb][uj] + iv * gv;
                const float hn = ov * tanh_fast(cn);
                sc[l][unb][uj] = cn;
                sh[l][unb][uj] = hn;
            }
            __syncthreads();   // h/c updated before next stage reads them
        }

        if (!enc) {
            const int td = t - SEQLEN;
            if (tid < NB) {
                float s = fcb[0];
                #pragma unroll
                for (int j = 0; j < HID; j += 4) {
                    const float4 wv = *(const float4*)&fcW[j];
                    const float4 hv = *(const float4*)&sh[LAYERS - 1][tid][j];
                    s += wv.x * hv.x + wv.y * hv.y + wv.z * hv.z + wv.w * hv.w;
                }
                out[(size_t)(b0 + tid) * PREDLEN + td] = s;
                sx[tid][0] = s;                       // feedback feature 0
            } else if (tid >= 64 && tid < 64 + NB * 3) {
                const int qd = tid - 64;
                const int nb = qd / 3, k = qd % 3;
                sx[nb][k + 1] = ff[((size_t)(b0 + nb) * PREDLEN + td) * 3 + k];
            }
            // top-of-loop __syncthreads() covers these sx writes
        }
    }
}

extern "C" void kernel_launch(void* const* d_in, const int* in_sizes, int n_in,
                              void* d_out, int out_size, void* d_ws, size_t ws_size,
                              hipStream_t stream) {
    const float* x    = (const float*)d_in[0];
    const float* ff   = (const float*)d_in[1];
    const float* eW0  = (const float*)d_in[2];
    const float* eWih = (const float*)d_in[3];
    const float* eWhh = (const float*)d_in[4];
    const float* ebih = (const float*)d_in[5];
    const float* ebhh = (const float*)d_in[6];
    const float* dW0  = (const float*)d_in[7];
    const float* dWih = (const float*)d_in[8];
    const float* dWhh = (const float*)d_in[9];
    const float* dbih = (const float*)d_in[10];
    const float* dbhh = (const float*)d_in[11];
    const float* fcW  = (const float*)d_in[12];
    const float* fcb  = (const float*)d_in[13];

    lstm_s2s<<<BATCH / NB, NTHR, 0, stream>>>(
        x, ff, eW0, eWih, eWhh, ebih, ebhh,
        dW0, dWih, dWhh, dbih, dbhh, fcW, fcb, (float*)d_out);
}

// Round 6
// 6481.078 us; speedup vs baseline: 15.4797x; 2.0349x over previous
//
#include <hip/hip_runtime.h>
#include <math.h>

// Seq2seq LSTM: 5-layer stack, HID=80, 336 enc + 48 dec steps, batch 512.
// R6: thread = (4 rows) x (k-quarter), T=320. Weights pre-packed into d_ws for
//     fully-coalesced wave loads; rolled loops (unroll 1) to stop the
//     hoist->spill blowup seen in R3/R4/R5; quad shfl reduce-scatter.
#define LAYERS  5
#define HID     80
#define GATES   320
#define INDIM   4
#define BATCH   512
#define SEQLEN  336
#define PREDLEN 48
#define TOT     (SEQLEN + PREDLEN)
#define NB      4
#define NTHR    320

// ---- packed workspace geometry (bytes) ----
#define ISLOTS  45                        // i-slots per ctx: l0:5, l1..4:10 each
#define NW4     (2 * ISLOTS * 4 * 320)    // float4 weight slots (both ctx)
#define OFF_B   ((size_t)NW4 * 16)        // bias sums: [ctx][l][320] floats
#define NBSUM   (2 * LAYERS * GATES)
#define OFF_P0  (OFF_B + (size_t)NBSUM * 4)   // W0 rows: [ctx][j][160] float4
#define NP04    (2 * 4 * 160)
#define WS_NEED (OFF_P0 + (size_t)NP04 * 16)
#define NPREP   (NW4 + NBSUM + NP04)

__device__ __forceinline__ float gate_act(float v, bool tg) {
    const float e = __expf(tg ? 2.0f * v : -v);
    const float r = 1.0f / (1.0f + e);
    return tg ? 1.0f - 2.0f * r : r;       // tanh(v) : sigmoid(v)
}
__device__ __forceinline__ float tanh_fast(float v) {
    return 1.0f - 2.0f / (1.0f + __expf(2.0f * v));
}

// ================= prep: pack weights/biases into ws =================
// weight slot layout: f4[ctx*57600 + slot*1280 + j*320 + tid]
//   tid=(m,q): row=4m+j.  l==0 (slots 0..4): k0=q*20+4i from Whh[0].
//   l>0 (slots 5+(l-1)*10 + i): q=(mat,half): mat0=Whh[l], mat1=Wih[l-1],
//   k0=half*40+4i.
__global__ void prep_pack(const float* __restrict__ eW0,  const float* __restrict__ eWih,
                          const float* __restrict__ eWhh, const float* __restrict__ ebih,
                          const float* __restrict__ ebhh,
                          const float* __restrict__ dW0,  const float* __restrict__ dWih,
                          const float* __restrict__ dWhh, const float* __restrict__ dbih,
                          const float* __restrict__ dbhh, float* __restrict__ ws)
{
    const int gid = blockIdx.x * 256 + threadIdx.x;
    if (gid < NW4) {
        float4* w4 = (float4*)ws;
        const int tid = gid % 320;
        const int j   = (gid / 320) & 3;
        const int ii  = (gid / 1280) % ISLOTS;
        const int ctx = gid / (1280 * ISLOTS);
        const float* Whh = ctx ? dWhh : eWhh;
        const float* Wih = ctx ? dWih : eWih;
        const int m = tid >> 2, q = tid & 3, row = 4 * m + j;
        const float* src;
        if (ii < 5) {                       // l == 0: 4-way k-slices of Whh[0]
            src = Whh + (size_t)row * HID + (q * 20 + 4 * ii);
        } else {
            const int l = (ii - 5) / 10 + 1, i = (ii - 5) % 10;
            const int mat = q >> 1, half = q & 1;
            const int k0 = half * 40 + 4 * i;
            src = mat ? (Wih + ((size_t)(l - 1) * GATES + row) * HID + k0)
                      : (Whh + ((size_t)l * GATES + row) * HID + k0);
        }
        w4[gid] = *(const float4*)src;
        return;
    }
    int g2 = gid - NW4;
    if (g2 < NBSUM) {                       // bias sums
        const int r = g2 % GATES, l = (g2 / GATES) % LAYERS, ctx = g2 / (GATES * LAYERS);
        const float* bi = ctx ? dbih : ebih;
        const float* bh = ctx ? dbhh : ebhh;
        ((float*)((char*)ws + OFF_B))[g2] = bi[l * GATES + r] + bh[l * GATES + r];
        return;
    }
    int g3 = g2 - NBSUM;
    if (g3 < NP04) {                        // W0 rows as float4
        const int m = g3 % 160, j = (g3 / 160) & 3, ctx = g3 / 640;
        const float* W0 = ctx ? dW0 : eW0;
        ((float4*)((char*)ws + OFF_P0))[g3] = *(const float4*)&W0[(4 * m + j) * INDIM];
    }
}

// ================= main persistent kernel =================
__global__ __launch_bounds__(NTHR) void lstm_main(
    const float* __restrict__ x,   const float* __restrict__ ff,
    const float* __restrict__ fcW, const float* __restrict__ fcb,
    const float* __restrict__ ws,  float* __restrict__ out)
{
    __shared__ __align__(16) float shc[2 * LAYERS * NB * HID];  // sh | sc
    __shared__ __align__(16) float sg[NB][GATES + 8];
    __shared__ __align__(16) float sx[NB][INDIM];
    float* sh = shc;
    float* sc = shc + LAYERS * NB * HID;

    const float4* w4  = (const float4*)ws;
    const float4* b4  = (const float4*)((const char*)ws + OFF_B);
    const float4* p04 = (const float4*)((const char*)ws + OFF_P0);

    const int tid = threadIdx.x;
    const int m   = tid >> 2;       // row-group: rows 4m..4m+3
    const int q   = tid & 3;        // k-quarter / matrix selector
    const int b0  = blockIdx.x * NB;

    for (int i = tid; i < 2 * LAYERS * NB * HID; i += NTHR) shc[i] = 0.0f;

    const bool is_tg = (m >= 40) && (m < 60);       // rows 160..239 = g gate
    const int  unb   = tid / HID, uj = tid % HID;   // update mapping

    #pragma unroll 1
    for (int t = 0; t < TOT; ++t) {
        const bool enc = (t < SEQLEN);
        const int  ctx = enc ? 0 : 1;

        if (enc && tid < NB * INDIM) {
            const int nb = tid >> 2, k = tid & 3;
            sx[nb][k] = x[((size_t)(b0 + nb) * SEQLEN + t) * INDIM + k];
        }
        __syncthreads();   // sx staged / dec feedback + state visible

        #pragma unroll 1
        for (int l = 0; l < LAYERS; ++l) {
            float a[4][4];
            #pragma unroll
            for (int j = 0; j < 4; ++j)
                #pragma unroll
                for (int b = 0; b < 4; ++b) a[j][b] = 0.0f;

            // h base for this lane (koff folded in) and packed-weight pointer
            const float* hbase;
            int ni;
            if (l == 0) { hbase = sh + q * 20;                              ni = 5; }
            else        { hbase = sh + (size_t)((q < 2 ? l : l - 1) * NB) * HID
                                  + (q & 1) * 40;                           ni = 10; }
            const float4* wp = w4 + (size_t)(ctx * ISLOTS + (l ? 5 + (l - 1) * 10 : 0)) * 1280 + tid;

            #pragma unroll 1
            for (int i = 0; i < ni; ++i) {
                float4 wv[4], hv[4];
                wv[0] = wp[0];   wv[1] = wp[320];
                wv[2] = wp[640]; wv[3] = wp[960];
                const float* hk = hbase + 4 * i;
                hv[0] = *(const float4*)(hk);
                hv[1] = *(const float4*)(hk + HID);
                hv[2] = *(const float4*)(hk + 2 * HID);
                hv[3] = *(const float4*)(hk + 3 * HID);
                #pragma unroll
                for (int j = 0; j < 4; ++j)
                    #pragma unroll
                    for (int b = 0; b < 4; ++b)
                        a[j][b] += wv[j].x * hv[b].x + wv[j].y * hv[b].y
                                 + wv[j].z * hv[b].z + wv[j].w * hv[b].w;
                wp += 1280;
            }

            if (l == 0 && q == 3) {          // input dot via packed W0 rows
                #pragma unroll
                for (int j = 0; j < 4; ++j) {
                    const float4 wv = p04[(ctx * 4 + j) * 160 + m];
                    #pragma unroll
                    for (int b = 0; b < 4; ++b)
                        a[j][b] += wv.x * sx[b][0] + wv.y * sx[b][1]
                                 + wv.z * sx[b][2] + wv.w * sx[b][3];
                }
            }

            // quad reduce-scatter: lane q ends with batch-q totals for its 4 rows
            float s[4];
            #pragma unroll
            for (int j = 0; j < 4; ++j) {
                float u0 = (q & 1) ? a[j][1] : a[j][0];
                float v0 = (q & 1) ? a[j][0] : a[j][1];
                u0 += __shfl_xor(v0, 1);
                float u1 = (q & 1) ? a[j][3] : a[j][2];
                float v1 = (q & 1) ? a[j][2] : a[j][3];
                u1 += __shfl_xor(v1, 1);
                float ke = (q & 2) ? u1 : u0;
                float v2 = (q & 2) ? u0 : u1;
                s[j] = ke + __shfl_xor(v2, 2);
            }

            const float4 bv = b4[(ctx * LAYERS + l) * 80 + m];
            const float g0 = gate_act(s[0] + bv.x, is_tg);
            const float g1 = gate_act(s[1] + bv.y, is_tg);
            const float g2 = gate_act(s[2] + bv.z, is_tg);
            const float g3 = gate_act(s[3] + bv.w, is_tg);
            *(float4*)&sg[q][4 * m] = make_float4(g0, g1, g2, g3);
            __syncthreads();   // gates ready

            {   // state update: thread -> (batch unb, unit uj)
                const float iv = sg[unb][uj];
                const float fv = sg[unb][uj + HID];
                const float gv = sg[unb][uj + 2 * HID];
                const float ov = sg[unb][uj + 3 * HID];
                float* scp = sc + (size_t)(l * NB + unb) * HID + uj;
                const float cn = fv * (*scp) + iv * gv;
                const float hn = ov * tanh_fast(cn);
                *scp = cn;
                sh[(size_t)(l * NB + unb) * HID + uj] = hn;
            }
            __syncthreads();   // h/c updated before next stage
        }

        if (!enc) {
            const int td = t - SEQLEN;
            if (tid < NB) {
                float s = fcb[0];
                const float* hv = sh + (size_t)((LAYERS - 1) * NB + tid) * HID;
                #pragma unroll
                for (int j = 0; j < HID; j += 4) {
                    const float4 wv = *(const float4*)&fcW[j];
                    const float4 h4 = *(const float4*)&hv[j];
                    s += wv.x * h4.x + wv.y * h4.y + wv.z * h4.z + wv.w * h4.w;
                }
                out[(size_t)(b0 + tid) * PREDLEN + td] = s;
                sx[tid][0] = s;                       // feedback feature 0
            } else if (tid >= 64 && tid < 64 + NB * 3) {
                const int qd = tid - 64;
                const int nb = qd / 3, k = qd % 3;
                sx[nb][k + 1] = ff[((size_t)(b0 + nb) * PREDLEN + td) * 3 + k];
            }
            // next iteration's top barrier covers these writes
        }
    }
}

// ================= fallback (R5, passed) if ws too small =================
#define FQK 20
#define FCHUNK(WPTR, HPTR, I)                                                    \
    do {                                                                         \
        const float4 wA = *(const float4*)((WPTR) + 4 * (I));                    \
        const float4 wB = *(const float4*)((WPTR) + HID + 4 * (I));              \
        const float* _h = (HPTR);                                                \
        const float4 h0 = *(const float4*)(_h + 0 * HID + 4 * (I));              \
        const float4 h1 = *(const float4*)(_h + 1 * HID + 4 * (I));              \
        const float4 h2 = *(const float4*)(_h + 2 * HID + 4 * (I));              \
        const float4 h3 = *(const float4*)(_h + 3 * HID + 4 * (I));              \
        a00 += wA.x * h0.x + wA.y * h0.y + wA.z * h0.z + wA.w * h0.w;            \
        a01 += wA.x * h1.x + wA.y * h1.y + wA.z * h1.z + wA.w * h1.w;            \
        a02 += wA.x * h2.x + wA.y * h2.y + wA.z * h2.z + wA.w * h2.w;            \
        a03 += wA.x * h3.x + wA.y * h3.y + wA.z * h3.z + wA.w * h3.w;            \
        a10 += wB.x * h0.x + wB.y * h0.y + wB.z * h0.z + wB.w * h0.w;            \
        a11 += wB.x * h1.x + wB.y * h1.y + wB.z * h1.z + wB.w * h1.w;            \
        a12 += wB.x * h2.x + wB.y * h2.y + wB.z * h2.z + wB.w * h2.w;            \
        a13 += wB.x * h3.x + wB.y * h3.y + wB.z * h3.z + wB.w * h3.w;            \
    } while (0)

__device__ __forceinline__ float rs4f(float v0, float v1, float v2, float v3, int q) {
    float u = (q & 1) ? v1 : v0;
    float s = (q & 1) ? v0 : v1;
    u += __shfl_xor(s, 1);
    float u2 = (q & 1) ? v3 : v2;
    float s2 = (q & 1) ? v2 : v3;
    u2 += __shfl_xor(s2, 1);
    float k = (q & 2) ? u2 : u;
    float s3 = (q & 2) ? u : u2;
    k += __shfl_xor(s3, 2);
    return k;
}

__global__ __launch_bounds__(640) void lstm_fb(
    const float* __restrict__ x,    const float* __restrict__ ff,
    const float* __restrict__ eW0,  const float* __restrict__ eWih,
    const float* __restrict__ eWhh, const float* __restrict__ ebih,
    const float* __restrict__ ebhh,
    const float* __restrict__ dW0,  const float* __restrict__ dWih,
    const float* __restrict__ dWhh, const float* __restrict__ dbih,
    const float* __restrict__ dbhh,
    const float* __restrict__ fcW,  const float* __restrict__ fcb,
    float* __restrict__ out)
{
    __shared__ __align__(16) float sh[LAYERS][NB][HID];
    __shared__ __align__(16) float sc[LAYERS][NB][HID];
    __shared__ __align__(16) float sg[NB][GATES + 1];
    __shared__ __align__(16) float sx[NB][INDIM];

    const int tid = threadIdx.x;
    const int q   = tid & 3;
    const int mm  = tid >> 2;
    const int r0  = 2 * mm;
    const int b0  = blockIdx.x * NB;

    for (int i = tid; i < LAYERS * NB * HID; i += 640) {
        (&sh[0][0][0])[i] = 0.0f;
        (&sc[0][0][0])[i] = 0.0f;
    }
    const bool is_tg = (r0 >= 2 * HID) && (r0 < 3 * HID);
    const int  unb = tid / HID, uj = tid % HID;

    float bs[2][LAYERS][2];
    #pragma unroll
    for (int l = 0; l < LAYERS; ++l) {
        bs[0][l][0] = ebih[l * GATES + r0]     + ebhh[l * GATES + r0];
        bs[0][l][1] = ebih[l * GATES + r0 + 1] + ebhh[l * GATES + r0 + 1];
        bs[1][l][0] = dbih[l * GATES + r0]     + dbhh[l * GATES + r0];
        bs[1][l][1] = dbih[l * GATES + r0 + 1] + dbhh[l * GATES + r0 + 1];
    }
    const float w0e0 = eW0[r0 * INDIM + q], w0e1 = eW0[(r0 + 1) * INDIM + q];
    const float w0d0 = dW0[r0 * INDIM + q], w0d1 = dW0[(r0 + 1) * INDIM + q];

    for (int t = 0; t < TOT; ++t) {
        const bool enc = (t < SEQLEN);
        const float* Wih = enc ? eWih : dWih;
        const float* Whh = enc ? eWhh : dWhh;
        if (enc && tid < NB * INDIM) {
            const int nb = tid / INDIM, k = tid % INDIM;
            sx[nb][k] = x[((size_t)(b0 + nb) * SEQLEN + t) * INDIM + k];
        }
        __syncthreads();
        #pragma unroll
        for (int l = 0; l < LAYERS; ++l) {
            float a00 = 0.f, a01 = 0.f, a02 = 0.f, a03 = 0.f;
            float a10 = 0.f, a11 = 0.f, a12 = 0.f, a13 = 0.f;
            {
                const float* wp = Whh + ((size_t)l * GATES + r0) * HID + q * FQK;
                const float* hp = &sh[l][0][q * FQK];
                #pragma unroll
                for (int i = 0; i < FQK / 4; ++i) FCHUNK(wp, hp, i);
            }
            if (l == 0) {
                const float wa = enc ? w0e0 : w0d0;
                const float wb = enc ? w0e1 : w0d1;
                a00 += wa * sx[0][q];  a01 += wa * sx[1][q];
                a02 += wa * sx[2][q];  a03 += wa * sx[3][q];
                a10 += wb * sx[0][q];  a11 += wb * sx[1][q];
                a12 += wb * sx[2][q];  a13 += wb * sx[3][q];
            } else {
                const float* wp = Wih + ((size_t)(l - 1) * GATES + r0) * HID + q * FQK;
                const float* hp = &sh[l - 1][0][q * FQK];
                #pragma unroll
                for (int i = 0; i < FQK / 4; ++i) FCHUNK(wp, hp, i);
            }
            const float s0 = rs4f(a00, a01, a02, a03, q);
            const float s1 = rs4f(a10, a11, a12, a13, q);
            const float bias0 = enc ? bs[0][l][0] : bs[1][l][0];
            const float bias1 = enc ? bs[0][l][1] : bs[1][l][1];
            sg[q][r0]     = gate_act(s0 + bias0, is_tg);
            sg[q][r0 + 1] = gate_act(s1 + bias1, is_tg);
            __syncthreads();
            if (tid < NB * HID) {
                const float iv = sg[unb][uj];
                const float fv = sg[unb][uj + HID];
                const float gv = sg[unb][uj + 2 * HID];
                const float ov = sg[unb][uj + 3 * HID];
                const float cn = fv * sc[l][unb][uj] + iv * gv;
                const float hn = ov * tanh_fast(cn);
                sc[l][unb][uj] = cn;
                sh[l][unb][uj] = hn;
            }
            __syncthreads();
        }
        if (!enc) {
            const int td = t - SEQLEN;
            if (tid < NB) {
                float s = fcb[0];
                #pragma unroll
                for (int j = 0; j < HID; j += 4) {
                    const float4 wv = *(const float4*)&fcW[j];
                    const float4 hv = *(const float4*)&sh[LAYERS - 1][tid][j];
                    s += wv.x * hv.x + wv.y * hv.y + wv.z * hv.z + wv.w * hv.w;
                }
                out[(size_t)(b0 + tid) * PREDLEN + td] = s;
                sx[tid][0] = s;
            } else if (tid >= 64 && tid < 64 + NB * 3) {
                const int qd = tid - 64;
                const int nb = qd / 3, k = qd % 3;
                sx[nb][k + 1] = ff[((size_t)(b0 + nb) * PREDLEN + td) * 3 + k];
            }
        }
    }
}

extern "C" void kernel_launch(void* const* d_in, const int* in_sizes, int n_in,
                              void* d_out, int out_size, void* d_ws, size_t ws_size,
                              hipStream_t stream) {
    const float* x    = (const float*)d_in[0];
    const float* ff   = (const float*)d_in[1];
    const float* eW0  = (const float*)d_in[2];
    const float* eWih = (const float*)d_in[3];
    const float* eWhh = (const float*)d_in[4];
    const float* ebih = (const float*)d_in[5];
    const float* ebhh = (const float*)d_in[6];
    const float* dW0  = (const float*)d_in[7];
    const float* dWih = (const float*)d_in[8];
    const float* dWhh = (const float*)d_in[9];
    const float* dbih = (const float*)d_in[10];
    const float* dbhh = (const float*)d_in[11];
    const float* fcW  = (const float*)d_in[12];
    const float* fcb  = (const float*)d_in[13];

    if (ws_size >= WS_NEED) {
        prep_pack<<<(NPREP + 255) / 256, 256, 0, stream>>>(
            eW0, eWih, eWhh, ebih, ebhh, dW0, dWih, dWhh, dbih, dbhh, (float*)d_ws);
        lstm_main<<<BATCH / NB, NTHR, 0, stream>>>(
            x, ff, fcW, fcb, (const float*)d_ws, (float*)d_out);
    } else {
        lstm_fb<<<BATCH / NB, 640, 0, stream>>>(
            x, ff, eW0, eWih, eWhh, ebih, ebhh,
            dW0, dWih, dWhh, dbih, dbhh, fcW, fcb, (float*)d_out);
    }
}

// Round 7
// 6319.320 us; speedup vs baseline: 15.8759x; 1.0256x over previous
//
#include <hip/hip_runtime.h>
#include <math.h>

// Seq2seq LSTM: 5-layer stack, HID=80, 336 enc + 48 dec steps, batch 512.
// R7: thread (m,q) owns unit m's 4 gate rows {m,m+80,m+160,m+240}, batch q.
//     After quartet reduce-scatter the cell update is lane-local: no sg
//     exchange, c thread-private, 1 barrier/stage (h ping-pong by t parity),
//     static activation types, depth-1 weight prefetch in rolled chunk loop.
#define LAYERS  5
#define HID     80
#define GATES   320
#define INDIM   4
#define BATCH   512
#define SEQLEN  336
#define PREDLEN 48
#define TOT     (SEQLEN + PREDLEN)
#define NB      4
#define NTHR    320

// ---- packed workspace geometry ----
// weights: f4[((ctx*45 + slot)*4 + j)*320 + tid]
//   tid=(m,q): m=tid>>2 unit, q=tid&3; j=gate (row = m+80j)
//   slot<5  (l==0): Whh[0] row, k0 = q*20 + 4*slot
//   slot>=5 (l=1..4, i=0..9): mat=q>>1 (0:Whh[l], 1:Wih[l-1]), k0=(q&1)*40+4i
#define ISLOTS  45
#define NW4     (2 * ISLOTS * 4 * 320)          // 115200 float4
#define OFF_B   ((size_t)NW4 * 16)              // bias float4[ctx*400 + l*80 + m]
#define NB4     (2 * LAYERS * 80)               // 800 float4
#define OFF_W0  (OFF_B + (size_t)NB4 * 16)      // w0 float[(ctx*4+j)*320 + tid]
#define NW0F    (2 * 4 * 320)                   // 2560 floats
#define WS_NEED (OFF_W0 + (size_t)NW0F * 4)
#define NPREP   (NW4 + NB4 + NW0F)

__device__ __forceinline__ float sigm(float v) { return 1.0f / (1.0f + __expf(-v)); }
__device__ __forceinline__ float tanh_fast(float v) {
    return 1.0f - 2.0f / (1.0f + __expf(2.0f * v));
}
__device__ __forceinline__ float gate_act(float v, bool tg) {
    const float e = __expf(tg ? 2.0f * v : -v);
    const float r = 1.0f / (1.0f + e);
    return tg ? 1.0f - 2.0f * r : r;
}

// ================= prep: pack weights/biases =================
__global__ void prep_pack(const float* __restrict__ eW0,  const float* __restrict__ eWih,
                          const float* __restrict__ eWhh, const float* __restrict__ ebih,
                          const float* __restrict__ ebhh,
                          const float* __restrict__ dW0,  const float* __restrict__ dWih,
                          const float* __restrict__ dWhh, const float* __restrict__ dbih,
                          const float* __restrict__ dbhh, float* __restrict__ ws)
{
    const int gid = blockIdx.x * 256 + threadIdx.x;
    if (gid < NW4) {
        const int tid  = gid % 320;
        const int j    = (gid / 320) & 3;
        const int slot = (gid / 1280) % ISLOTS;
        const int ctx  = gid / (1280 * ISLOTS);
        const float* Whh = ctx ? dWhh : eWhh;
        const float* Wih = ctx ? dWih : eWih;
        const int m = tid >> 2, q = tid & 3;
        const int row = m + 80 * j;
        const float* src;
        if (slot < 5) {
            src = Whh + (size_t)row * HID + (q * 20 + 4 * slot);
        } else {
            const int l = (slot - 5) / 10 + 1, i = (slot - 5) % 10;
            const int k0 = (q & 1) * 40 + 4 * i;
            src = (q >> 1) ? (Wih + ((size_t)(l - 1) * GATES + row) * HID + k0)
                           : (Whh + ((size_t)l * GATES + row) * HID + k0);
        }
        ((float4*)ws)[gid] = *(const float4*)src;
        return;
    }
    int g2 = gid - NW4;
    if (g2 < NB4) {             // bias float4 per (ctx,l,m): rows m+80j
        const int m = g2 % 80, l = (g2 / 80) % LAYERS, ctx = g2 / 400;
        const float* bi = ctx ? dbih : ebih;
        const float* bh = ctx ? dbhh : ebhh;
        float4 v;
        v.x = bi[l * GATES + m]       + bh[l * GATES + m];
        v.y = bi[l * GATES + m + 80]  + bh[l * GATES + m + 80];
        v.z = bi[l * GATES + m + 160] + bh[l * GATES + m + 160];
        v.w = bi[l * GATES + m + 240] + bh[l * GATES + m + 240];
        ((float4*)((char*)ws + OFF_B))[g2] = v;
        return;
    }
    int g3 = g2 - NB4;
    if (g3 < NW0F) {            // W0 scalar per (ctx,j,tid): W0[m+80j, q]
        const int tid = g3 % 320, j = (g3 / 320) & 3, ctx = g3 / 1280;
        const int m = tid >> 2, q = tid & 3;
        const float* W0 = ctx ? dW0 : eW0;
        ((float*)((char*)ws + OFF_W0))[g3] = W0[(m + 80 * j) * INDIM + q];
    }
}

// ================= main persistent kernel =================
__global__ __launch_bounds__(NTHR) void lstm_main(
    const float* __restrict__ x,   const float* __restrict__ ff,
    const float* __restrict__ fcW, const float* __restrict__ fcb,
    const float* __restrict__ ws,  float* __restrict__ out)
{
    // h ping-pong buffers + private c, all [l][batch][unit] flattened (l*320+b*80+u)
    __shared__ __align__(16) float hA[LAYERS * NB * HID];
    __shared__ __align__(16) float hB[LAYERS * NB * HID];
    __shared__ __align__(16) float cS[LAYERS * NB * HID];
    __shared__ __align__(16) float sx[NB][INDIM];

    const float4* w4  = (const float4*)ws;
    const float4* b4  = (const float4*)((const char*)ws + OFF_B);
    const float*  w0f = (const float*)((const char*)ws + OFF_W0);

    const int tid = threadIdx.x;
    const int m   = tid >> 2;        // unit
    const int q   = tid & 3;         // k-quarter AND owned batch
    const int b0  = blockIdx.x * NB;

    for (int i = tid; i < LAYERS * NB * HID; i += NTHR) {
        hA[i] = 0.0f; hB[i] = 0.0f; cS[i] = 0.0f;
    }
    if (tid < NB * INDIM) {          // stage sx for t=0
        const int nb = tid >> 2, k = tid & 3;
        sx[nb][k] = x[((size_t)(b0 + nb) * SEQLEN + 0) * INDIM + k];
    }
    __syncthreads();

    #pragma unroll 1
    for (int t = 0; t < TOT; ++t) {
        const bool enc = (t < SEQLEN);
        const int  ctx = enc ? 0 : 1;
        float* cur = (t & 1) ? hB : hA;
        float* prv = (t & 1) ? hA : hB;

        float xreg = 0.0f;           // early-loaded x[t+1] element (tid<16)
        const bool do_stage = enc && (t + 1 < SEQLEN) && (tid < NB * INDIM);

        #pragma unroll 1
        for (int l = 0; l < LAYERS; ++l) {
            if (l == 0 && do_stage) {
                const int nb = tid >> 2, k = tid & 3;
                xreg = x[((size_t)(b0 + nb) * SEQLEN + (t + 1)) * INDIM + k];
            }

            float a[4][4];           // [gate j][batch b]
            #pragma unroll
            for (int j = 0; j < 4; ++j)
                #pragma unroll
                for (int b = 0; b < 4; ++b) a[j][b] = 0.0f;

            // per-lane h source and packed-weight pointer
            const float* hb;
            int ni;
            if (l == 0) { hb = prv + q * 20;                       ni = 5;  }
            else        { hb = ((q >> 1) ? cur + (l - 1) * 320
                                         : prv + l * 320) + (q & 1) * 40;
                                                                   ni = 10; }
            const int slotbase = ctx * ISLOTS + (l ? 5 + (l - 1) * 10 : 0);
            const float4* wp = w4 + (size_t)slotbase * 1280 + tid;

            float4 wvc[4];
            wvc[0] = wp[0];   wvc[1] = wp[320];
            wvc[2] = wp[640]; wvc[3] = wp[960];

            #pragma unroll 1
            for (int i = 0; i < ni; ++i) {
                const float4* np = wp + 1280;      // depth-1 prefetch (overrun
                float4 wvn[4];                     //  lands in next slot/bias: safe)
                wvn[0] = np[0];   wvn[1] = np[320];
                wvn[2] = np[640]; wvn[3] = np[960];
                const float* hk = hb + 4 * i;
                float4 hv[4];
                hv[0] = *(const float4*)(hk);
                hv[1] = *(const float4*)(hk + 80);
                hv[2] = *(const float4*)(hk + 160);
                hv[3] = *(const float4*)(hk + 240);
                #pragma unroll
                for (int j = 0; j < 4; ++j)
                    #pragma unroll
                    for (int b = 0; b < 4; ++b)
                        a[j][b] += wvc[j].x * hv[b].x + wvc[j].y * hv[b].y
                                 + wvc[j].z * hv[b].z + wvc[j].w * hv[b].w;
                #pragma unroll
                for (int j = 0; j < 4; ++j) wvc[j] = wvn[j];
                wp = np;
            }

            if (l == 0) {            // x @ W0^T: lane q covers input dim q
                #pragma unroll
                for (int j = 0; j < 4; ++j) {
                    const float w0v = w0f[(ctx * 4 + j) * 320 + tid];
                    #pragma unroll
                    for (int b = 0; b < 4; ++b)
                        a[j][b] += w0v * sx[b][q];
                }
            }

            // quartet reduce-scatter: lane q ends with batch-q totals (4 gates)
            float s[4];
            #pragma unroll
            for (int j = 0; j < 4; ++j) {
                float u0 = (q & 1) ? a[j][1] : a[j][0];
                float v0 = (q & 1) ? a[j][0] : a[j][1];
                u0 += __shfl_xor(v0, 1);
                float u1 = (q & 1) ? a[j][3] : a[j][2];
                float v1 = (q & 1) ? a[j][2] : a[j][3];
                u1 += __shfl_xor(v1, 1);
                float ke = (q & 2) ? u1 : u0;
                float v2 = (q & 2) ? u0 : u1;
                s[j] = ke + __shfl_xor(v2, 2);
            }

            // lane-local activation + cell update (i,f,g,o statically typed)
            const float4 bv = b4[(ctx * LAYERS + l) * 80 + m];
            const float gi = sigm(s[0] + bv.x);
            const float gf = sigm(s[1] + bv.y);
            const float gg = tanh_fast(s[2] + bv.z);
            const float go = sigm(s[3] + bv.w);
            const int   sidx = l * 320 + q * 80 + m;
            const float cn = gf * cS[sidx] + gi * gg;
            const float hn = go * tanh_fast(cn);
            cS[sidx]  = cn;          // thread-private cell
            cur[sidx] = hn;          // shared h (read next stage / next t)

            if (l == 3 && do_stage) {
                const int nb = tid >> 2, k = tid & 3;
                sx[nb][k] = xreg;    // covered by this stage's barrier
            }
            __syncthreads();
        }

        if (!enc) {
            const int td = t - SEQLEN;
            if (tid < NB) {          // pred = h_top @ fcW + fcb; feedback
                float s = fcb[0];
                const float* hvp = cur + 4 * 320 + tid * 80;
                #pragma unroll
                for (int jj = 0; jj < HID; jj += 4) {
                    const float4 wv4 = *(const float4*)&fcW[jj];
                    const float4 h4  = *(const float4*)&hvp[jj];
                    s += wv4.x * h4.x + wv4.y * h4.y + wv4.z * h4.z + wv4.w * h4.w;
                }
                out[(size_t)(b0 + tid) * PREDLEN + td] = s;
                sx[tid][0] = s;
            } else if (tid >= 64 && tid < 64 + NB * 3) {
                const int qd = tid - 64;
                const int nb = qd / 3, k = qd % 3;
                sx[nb][k + 1] = ff[((size_t)(b0 + nb) * PREDLEN + td) * 3 + k];
            }
            __syncthreads();         // sx feedback ready for next t's stage 0
        }
    }
}

// ================= fallback (R5 kernel, proven) if ws too small =================
#define FQK 20
#define FCHUNK(WPTR, HPTR, I)                                                    \
    do {                                                                         \
        const float4 wA = *(const float4*)((WPTR) + 4 * (I));                    \
        const float4 wB = *(const float4*)((WPTR) + HID + 4 * (I));              \
        const float* _h = (HPTR);                                                \
        const float4 h0 = *(const float4*)(_h + 0 * HID + 4 * (I));              \
        const float4 h1 = *(const float4*)(_h + 1 * HID + 4 * (I));              \
        const float4 h2 = *(const float4*)(_h + 2 * HID + 4 * (I));              \
        const float4 h3 = *(const float4*)(_h + 3 * HID + 4 * (I));              \
        a00 += wA.x * h0.x + wA.y * h0.y + wA.z * h0.z + wA.w * h0.w;            \
        a01 += wA.x * h1.x + wA.y * h1.y + wA.z * h1.z + wA.w * h1.w;            \
        a02 += wA.x * h2.x + wA.y * h2.y + wA.z * h2.z + wA.w * h2.w;            \
        a03 += wA.x * h3.x + wA.y * h3.y + wA.z * h3.z + wA.w * h3.w;            \
        a10 += wB.x * h0.x + wB.y * h0.y + wB.z * h0.z + wB.w * h0.w;            \
        a11 += wB.x * h1.x + wB.y * h1.y + wB.z * h1.z + wB.w * h1.w;            \
        a12 += wB.x * h2.x + wB.y * h2.y + wB.z * h2.z + wB.w * h2.w;            \
        a13 += wB.x * h3.x + wB.y * h3.y + wB.z * h3.z + wB.w * h3.w;            \
    } while (0)

__device__ __forceinline__ float rs4f(float v0, float v1, float v2, float v3, int q) {
    float u = (q & 1) ? v1 : v0;
    float s = (q & 1) ? v0 : v1;
    u += __shfl_xor(s, 1);
    float u2 = (q & 1) ? v3 : v2;
    float s2 = (q & 1) ? v2 : v3;
    u2 += __shfl_xor(s2, 1);
    float k = (q & 2) ? u2 : u;
    float s3 = (q & 2) ? u : u2;
    k += __shfl_xor(s3, 2);
    return k;
}

__global__ __launch_bounds__(640) void lstm_fb(
    const float* __restrict__ x,    const float* __restrict__ ff,
    const float* __restrict__ eW0,  const float* __restrict__ eWih,
    const float* __restrict__ eWhh, const float* __restrict__ ebih,
    const float* __restrict__ ebhh,
    const float* __restrict__ dW0,  const float* __restrict__ dWih,
    const float* __restrict__ dWhh, const float* __restrict__ dbih,
    const float* __restrict__ dbhh,
    const float* __restrict__ fcW,  const float* __restrict__ fcb,
    float* __restrict__ out)
{
    __shared__ __align__(16) float sh[LAYERS][NB][HID];
    __shared__ __align__(16) float sc[LAYERS][NB][HID];
    __shared__ __align__(16) float sg[NB][GATES + 1];
    __shared__ __align__(16) float sx[NB][INDIM];

    const int tid = threadIdx.x;
    const int q   = tid & 3;
    const int mm  = tid >> 2;
    const int r0  = 2 * mm;
    const int b0  = blockIdx.x * NB;

    for (int i = tid; i < LAYERS * NB * HID; i += 640) {
        (&sh[0][0][0])[i] = 0.0f;
        (&sc[0][0][0])[i] = 0.0f;
    }
    const bool is_tg = (r0 >= 2 * HID) && (r0 < 3 * HID);
    const int  unb = tid / HID, uj = tid % HID;

    float bs[2][LAYERS][2];
    #pragma unroll
    for (int l = 0; l < LAYERS; ++l) {
        bs[0][l][0] = ebih[l * GATES + r0]     + ebhh[l * GATES + r0];
        bs[0][l][1] = ebih[l * GATES + r0 + 1] + ebhh[l * GATES + r0 + 1];
        bs[1][l][0] = dbih[l * GATES + r0]     + dbhh[l * GATES + r0];
        bs[1][l][1] = dbih[l * GATES + r0 + 1] + dbhh[l * GATES + r0 + 1];
    }
    const float w0e0 = eW0[r0 * INDIM + q], w0e1 = eW0[(r0 + 1) * INDIM + q];
    const float w0d0 = dW0[r0 * INDIM + q], w0d1 = dW0[(r0 + 1) * INDIM + q];

    for (int t = 0; t < TOT; ++t) {
        const bool enc = (t < SEQLEN);
        const float* Wih = enc ? eWih : dWih;
        const float* Whh = enc ? eWhh : dWhh;
        if (enc && tid < NB * INDIM) {
            const int nb = tid / INDIM, k = tid % INDIM;
            sx[nb][k] = x[((size_t)(b0 + nb) * SEQLEN + t) * INDIM + k];
        }
        __syncthreads();
        #pragma unroll
        for (int l = 0; l < LAYERS; ++l) {
            float a00 = 0.f, a01 = 0.f, a02 = 0.f, a03 = 0.f;
            float a10 = 0.f, a11 = 0.f, a12 = 0.f, a13 = 0.f;
            {
                const float* wp = Whh + ((size_t)l * GATES + r0) * HID + q * FQK;
                const float* hp = &sh[l][0][q * FQK];
                #pragma unroll
                for (int i = 0; i < FQK / 4; ++i) FCHUNK(wp, hp, i);
            }
            if (l == 0) {
                const float wa = enc ? w0e0 : w0d0;
                const float wb = enc ? w0e1 : w0d1;
                a00 += wa * sx[0][q];  a01 += wa * sx[1][q];
                a02 += wa * sx[2][q];  a03 += wa * sx[3][q];
                a10 += wb * sx[0][q];  a11 += wb * sx[1][q];
                a12 += wb * sx[2][q];  a13 += wb * sx[3][q];
            } else {
                const float* wp = Wih + ((size_t)(l - 1) * GATES + r0) * HID + q * FQK;
                const float* hp = &sh[l - 1][0][q * FQK];
                #pragma unroll
                for (int i = 0; i < FQK / 4; ++i) FCHUNK(wp, hp, i);
            }
            const float s0 = rs4f(a00, a01, a02, a03, q);
            const float s1 = rs4f(a10, a11, a12, a13, q);
            const float bias0 = enc ? bs[0][l][0] : bs[1][l][0];
            const float bias1 = enc ? bs[0][l][1] : bs[1][l][1];
            sg[q][r0]     = gate_act(s0 + bias0, is_tg);
            sg[q][r0 + 1] = gate_act(s1 + bias1, is_tg);
            __syncthreads();
            if (tid < NB * HID) {
                const float iv = sg[unb][uj];
                const float fv = sg[unb][uj + HID];
                const float gv = sg[unb][uj + 2 * HID];
                const float ov = sg[unb][uj + 3 * HID];
                const float cn = fv * sc[l][unb][uj] + iv * gv;
                const float hn = ov * tanh_fast(cn);
                sc[l][unb][uj] = cn;
                sh[l][unb][uj] = hn;
            }
            __syncthreads();
        }
        if (!enc) {
            const int td = t - SEQLEN;
            if (tid < NB) {
                float s = fcb[0];
                #pragma unroll
                for (int j = 0; j < HID; j += 4) {
                    const float4 wv = *(const float4*)&fcW[j];
                    const float4 hv = *(const float4*)&sh[LAYERS - 1][tid][j];
                    s += wv.x * hv.x + wv.y * hv.y + wv.z * hv.z + wv.w * hv.w;
                }
                out[(size_t)(b0 + tid) * PREDLEN + td] = s;
                sx[tid][0] = s;
            } else if (tid >= 64 && tid < 64 + NB * 3) {
                const int qd = tid - 64;
                const int nb = qd / 3, k = qd % 3;
                sx[nb][k + 1] = ff[((size_t)(b0 + nb) * PREDLEN + td) * 3 + k];
            }
        }
    }
}

extern "C" void kernel_launch(void* const* d_in, const int* in_sizes, int n_in,
                              void* d_out, int out_size, void* d_ws, size_t ws_size,
                              hipStream_t stream) {
    const float* x    = (const float*)d_in[0];
    const float* ff   = (const float*)d_in[1];
    const float* eW0  = (const float*)d_in[2];
    const float* eWih = (const float*)d_in[3];
    const float* eWhh = (const float*)d_in[4];
    const float* ebih = (const float*)d_in[5];
    const float* ebhh = (const float*)d_in[6];
    const float* dW0  = (const float*)d_in[7];
    const float* dWih = (const float*)d_in[8];
    const float* dWhh = (const float*)d_in[9];
    const float* dbih = (const float*)d_in[10];
    const float* dbhh = (const float*)d_in[11];
    const float* fcW  = (const float*)d_in[12];
    const float* fcb  = (const float*)d_in[13];

    if (ws_size >= WS_NEED) {
        prep_pack<<<(NPREP + 255) / 256, 256, 0, stream>>>(
            eW0, eWih, eWhh, ebih, ebhh, dW0, dWih, dWhh, dbih, dbhh, (float*)d_ws);
        lstm_main<<<BATCH / NB, NTHR, 0, stream>>>(
            x, ff, fcW, fcb, (const float*)d_ws, (float*)d_out);
    } else {
        lstm_fb<<<BATCH / NB, 640, 0, stream>>>(
            x, ff, eW0, eWih, eWhh, ebih, ebhh,
            dW0, dWih, dWhh, dbih, dbhh, fcW, fcb, (float*)d_out);
    }
}